// Round 1
// baseline (230.985 us; speedup 1.0000x reference)
//
#include <hip/hip_runtime.h>
#include <hip/hip_bf16.h>

#define BB 8
#define NLOG 16
#define NN 65536
#define KK 9
#define FF 32
#define OO 64
#define DD 288            // K*F
#define WSTR 296          // padded W row stride (shorts)
#define CHUNK 64          // points per block-chunk
#define THREADS 256
#define NBLOCKS 1024
#define TOTALP (BB * NN)          // 524288
#define NCHUNKS (TOTALP / CHUNK)  // 8192

typedef float f32x4 __attribute__((ext_vector_type(4)));
typedef short s16x8 __attribute__((ext_vector_type(8)));
typedef short s16x4 __attribute__((ext_vector_type(4)));

static __device__ __forceinline__ short f2bf(float f) {
    union { __hip_bfloat16 h; short s; } u;
    u.h = __float2bfloat16(f);
    return u.s;
}

static __device__ __forceinline__ float elu1(float x) {
    float e = __expf(fminf(x, 0.f)) - 1.f;
    return x > 0.f ? x : e;
}

__global__ __launch_bounds__(THREADS, 2) void paiconv_fused(
    const float* __restrict__ x,
    const int* __restrict__ nbr,
    const float* __restrict__ v,
    const float* __restrict__ aw,
    const float* __restrict__ W,
    const float* __restrict__ bias,
    float* __restrict__ out)
{
    __shared__ short Wl[OO * WSTR];     // 37888 B, W as bf16, padded rows
    __shared__ float AJ[CHUNK * 81];    // 20736 B, adjw per point (stride 81 -> conflict-free)
    __shared__ float BL[OO];            // 256 B

    const int tid = threadIdx.x;

    // ---- stage W (fp32 global -> bf16 LDS), once per block ----
    for (int e = tid; e < OO * DD / 4; e += THREADS) {
        int o = e / 72;
        int d4 = (e - o * 72) * 4;
        const f32x4 wv = *(const f32x4*)(W + o * DD + d4);
        s16x4 p;
        p.x = f2bf(wv.x); p.y = f2bf(wv.y); p.z = f2bf(wv.z); p.w = f2bf(wv.w);
        *(s16x4*)(&Wl[o * WSTR + d4]) = p;
    }
    if (tid < OO) BL[tid] = bias[tid];

    const int lane = tid & 63;
    const int wid  = tid >> 6;
    const int l15  = lane & 15;       // A row (point in 16-tile) / C col (o in 16-group)
    const int fg   = lane >> 4;       // k-octet group
    const int fo   = fg * 8;          // f offset of this lane's octet
    const int pl   = wid * 16 + l15;  // point within chunk

    for (int ci = blockIdx.x; ci < NCHUNKS; ci += NBLOCKS) {
        const int cbase = ci * CHUNK;
        __syncthreads();  // previous tile done with AJ (first iter: W staged)

        // ---- cooperative adjacency: AJ[p*81 + k*9 + t] = sum_s v[n,s]*aw[s,k,t] ----
        for (int e = tid; e < CHUNK * 81; e += THREADS) {
            int p = e / 81;
            int r = e - p * 81;
            int n = (cbase + p) & (NN - 1);
            float s = 0.f;
            #pragma unroll
            for (int si = 0; si < 8; ++si)
                s += v[n * 8 + si] * aw[si * 81 + r];
            AJ[e] = s;
        }
        __syncthreads();

        const int P = cbase + pl;
        const int b = P >> NLOG;
        const int* nip = nbr + (size_t)P * KK;
        const float* xb = x + (((size_t)b) << NLOG) * FF;

        // ---- gather neighbor features: G[k][j] = x[b, idx[k], fo+j] ----
        float G[KK][8];
        #pragma unroll
        for (int k = 0; k < KK; ++k) {
            const int row = nip[k];
            const float* src = xb + (size_t)row * FF + fo;
            f32x4 g0 = *(const f32x4*)(src);
            f32x4 g1 = *(const f32x4*)(src + 4);
            G[k][0] = g0.x; G[k][1] = g0.y; G[k][2] = g0.z; G[k][3] = g0.w;
            G[k][4] = g1.x; G[k][5] = g1.y; G[k][6] = g1.z; G[k][7] = g1.w;
        }

        f32x4 acc0 = {0.f, 0.f, 0.f, 0.f};
        f32x4 acc1 = {0.f, 0.f, 0.f, 0.f};
        f32x4 acc2 = {0.f, 0.f, 0.f, 0.f};
        f32x4 acc3 = {0.f, 0.f, 0.f, 0.f};

        // ---- K-loop: 9 t-tiles of 32 (one t each since F==32) ----
        #pragma unroll
        for (int t = 0; t < KK; ++t) {
            float xn[8] = {0.f, 0.f, 0.f, 0.f, 0.f, 0.f, 0.f, 0.f};
            #pragma unroll
            for (int k = 0; k < KK; ++k) {
                const float a = AJ[pl * 81 + k * 9 + t];
                #pragma unroll
                for (int j = 0; j < 8; ++j) xn[j] += G[k][j] * a;
            }
            // elu + convert to bf16 A-fragment (lane: row=l15, k=fo+j within tile t)
            s16x8 af;
            #pragma unroll
            for (int j = 0; j < 8; ++j) af[j] = f2bf(elu1(xn[j]));

            // B-fragments: 8 consecutive bf16 from W row (ot*16+l15), d = t*32+fo
            const short* wrow = &Wl[l15 * WSTR + t * FF + fo];
            s16x8 b0 = *(const s16x8*)(wrow);
            s16x8 b1 = *(const s16x8*)(wrow + 16 * WSTR);
            s16x8 b2 = *(const s16x8*)(wrow + 32 * WSTR);
            s16x8 b3 = *(const s16x8*)(wrow + 48 * WSTR);
            acc0 = __builtin_amdgcn_mfma_f32_16x16x32_bf16(af, b0, acc0, 0, 0, 0);
            acc1 = __builtin_amdgcn_mfma_f32_16x16x32_bf16(af, b1, acc1, 0, 0, 0);
            acc2 = __builtin_amdgcn_mfma_f32_16x16x32_bf16(af, b2, acc2, 0, 0, 0);
            acc3 = __builtin_amdgcn_mfma_f32_16x16x32_bf16(af, b3, acc3, 0, 0, 0);
        }

        // ---- epilogue: bias + elu + padding mask + store (C: col=l15, row=fg*4+r) ----
        #pragma unroll
        for (int ot = 0; ot < 4; ++ot) {
            const f32x4 a = (ot == 0) ? acc0 : (ot == 1) ? acc1 : (ot == 2) ? acc2 : acc3;
            const int o = ot * 16 + l15;
            const float bv = BL[o];
            #pragma unroll
            for (int r = 0; r < 4; ++r) {
                const int Pp = cbase + wid * 16 + fg * 4 + r;
                float val = elu1(a[r] + bv);
                if ((Pp & (NN - 1)) == (NN - 1)) val = 0.f;
                out[(size_t)Pp * OO + o] = val;
            }
        }
    }
}

extern "C" void kernel_launch(void* const* d_in, const int* in_sizes, int n_in,
                              void* d_out, int out_size, void* d_ws, size_t ws_size,
                              hipStream_t stream) {
    const float* x    = (const float*)d_in[0];
    // d_in[1] = t_vertex (unused in forward)
    const int*   nbr  = (const int*)d_in[2];
    const float* v    = (const float*)d_in[3];
    const float* aw   = (const float*)d_in[4];
    const float* W    = (const float*)d_in[5];
    const float* bias = (const float*)d_in[6];
    float* out = (float*)d_out;

    hipLaunchKernelGGL(paiconv_fused, dim3(NBLOCKS), dim3(THREADS), 0, stream,
                       x, nbr, v, aw, W, bias, out);
}